// Round 6
// baseline (387.031 us; speedup 1.0000x reference)
//
#include <hip/hip_runtime.h>

// binning_CRVD forward: out[b,c,hw] = sum_j P[c/4][j] * x[b, j*16 + c, hw]
// B=16, C_in=64, C_out=16, H=W=256, fp32. Pure streaming, memory-bound:
// 256 MiB read + 64 MiB write -> ~51 us floor at 6.3 TB/s.
// Group order along c/4: gb (0-3), b (4-7), r (8-11), gr (12-15).
//
// Thread decomposition: thread t in [0, 2^20) owns (hw4 = t & 16383,
// plane = t >> 14) where plane in [0,64) = (b0 = plane>>4, c = plane&15).
// It produces outputs for b = b0, b0+4, b0+8, b0+12 at fixed (c, hw4):
// c is thread-invariant -> weight select + load hoisted out of the loop.

constexpr int HW4      = 256 * 256 / 4;   // 16384 float4 per plane
constexpr int LOG2_HW4 = 14;

// native clang vector type: __builtin_nontemporal_store requires it
// (HIP's float4 is a class and is rejected)
typedef float f32x4 __attribute__((ext_vector_type(4)));

__global__ __launch_bounds__(256)
void binning_CRVD_kernel(const f32x4* __restrict__ x,
                         const float* __restrict__ pgb,
                         const float* __restrict__ pb,
                         const float* __restrict__ pr,
                         const float* __restrict__ pgr,
                         f32x4* __restrict__ out)
{
    const int t     = blockIdx.x * 256 + threadIdx.x;  // 0 .. 2^20-1
    const int hw    = t & (HW4 - 1);
    const int plane = t >> LOG2_HW4;    // 0..63
    const int c     = plane & 15;
    const int b0    = plane >> 4;       // 0..3

    // weight select is wave-uniform (a 256-thread block spans 1/64th of a
    // plane) and loaded exactly once per thread
    const float* p = (c < 8) ? ((c < 4) ? pgb : pb)
                             : ((c < 12) ? pr : pgr);
    const float w0 = p[0], w1 = p[1], w2 = p[2], w3 = p[3];

#pragma unroll
    for (int i = 0; i < 4; ++i) {
        const int b = b0 + 4 * i;
        const f32x4* xp = x + (((size_t)(b * 64 + c)) << LOG2_HW4) + hw;
        const f32x4 t0 = xp[0 * 16 * HW4];
        const f32x4 t1 = xp[1 * 16 * HW4];
        const f32x4 t2 = xp[2 * 16 * HW4];
        const f32x4 t3 = xp[3 * 16 * HW4];

        f32x4 o = w0 * t0 + w1 * t1 + w2 * t2 + w3 * t3;

        // output is write-once, never re-read: nontemporal keeps the store
        // stream from evicting the input stream in L2/L3
        __builtin_nontemporal_store(o, &out[(((size_t)(b * 16 + c)) << LOG2_HW4) + hw]);
    }
}

extern "C" void kernel_launch(void* const* d_in, const int* in_sizes, int n_in,
                              void* d_out, int out_size, void* d_ws, size_t ws_size,
                              hipStream_t stream)
{
    const f32x4* x   = (const f32x4*)d_in[0];
    const float* pgb = (const float*)d_in[1];
    const float* pb  = (const float*)d_in[2];
    const float* pr  = (const float*)d_in[3];
    const float* pgr = (const float*)d_in[4];

    // 2^20 threads, 4 f32x4 outputs each = 4,194,304 float4 = out_size/4
    binning_CRVD_kernel<<<4096, 256, 0, stream>>>(
        x, pgb, pb, pr, pgr, (f32x4*)d_out);
}